// Round 12
// baseline (75.949 us; speedup 1.0000x reference)
//
#include <hip/hip_runtime.h>
#include <stdint.h>

// Problem constants
#define MDIM 8192   // batch
#define KDIM 512    // input size
#define TDIM 2080   // tril param count (64*65/2)
#define NPAD 2176   // TDIM padded to multiple of 128 (17*128)
#define MSZ  64     // matrix size
#define NSC  1040   // chol-row dwords per batch (TDIM/2)

typedef __attribute__((ext_vector_type(8))) __bf16 bf16x8;
typedef __attribute__((ext_vector_type(4))) float  f32x4;

__device__ __forceinline__ unsigned short f2bf(float f) {
    unsigned int u = __float_as_uint(f);
    u += 0x7fffu + ((u >> 16) & 1u);   // round-to-nearest-even
    return (unsigned short)(u >> 16);
}

// tril row index from linear tril index n
__device__ __forceinline__ int tril_row(int n) {
    int i = (int)((sqrtf((float)(8 * n + 1)) - 1.0f) * 0.5f);
    while ((i + 1) * (i + 2) / 2 <= n) ++i;
    while (i * (i + 1) / 2 > n) --i;
    return i;
}

// swizzled LDS byte address for L[i][j] in the [64][64] bf16 tile
__device__ __forceinline__ int swz_addr(int i, int j) {
    int ch = ((j >> 3) ^ i) & 7;                         // swizzled 16B chunk
    return i * 128 + (ch << 4) + ((j & 7) * 2);
}

// ---------------- convert kernel: W + bias/diag tables + scatter table ONLY ----------------
#define NW4 (NPAD * KDIM / 4)        // 278528 float4 chunks of padded W
#define NT4 (NPAD / 4)               // 544 table chunks

__global__ __launch_bounds__(256) void convertw_kernel(const float* __restrict__ W,
                                                       const float* __restrict__ b,
                                                       unsigned short* __restrict__ wb,
                                                       float* __restrict__ biasf,
                                                       float* __restrict__ diagm,
                                                       unsigned int* __restrict__ sidx) {
    int idx = blockIdx.x * 256 + threadIdx.x;
    if (idx < NW4) {
        int n = (idx * 4) >> 9;                          // W row (KDIM=512)
        ushort4 o = make_ushort4(0, 0, 0, 0);
        if (n < TDIM) {
            float4 v = reinterpret_cast<const float4*>(W)[idx];
            o = make_ushort4(f2bf(v.x), f2bf(v.y), f2bf(v.z), f2bf(v.w));
        }
        reinterpret_cast<ushort4*>(wb)[idx] = o;
    } else if (idx < NW4 + NT4) {
        int t = idx - NW4;
#pragma unroll
        for (int r = 0; r < 4; ++r) {
            int n = t * 4 + r;
            float bv = 0.f, dm = 0.f;
            if (n < TDIM) {
                bv = b[n];
                int i = tril_row(n);
                dm = (n - i * (i + 1) / 2 == i) ? 1.f : 0.f;
            }
            biasf[n] = bv;
            diagm[n] = dm;
        }
    } else {
        int t = idx - NW4 - NT4;                         // scatter-table entry (chol dword)
        if (t < NSC) {
            int n = 2 * t;
            int i = tril_row(n);
            int j = n - i * (i + 1) / 2;
            int a0 = swz_addr(i, j);
            int i2 = i, j2 = j + 1;
            if (j2 > i2) { i2 = i + 1; j2 = 0; }
            int a1 = swz_addr(i2, j2);
            sidx[t] = (unsigned int)a0 | ((unsigned int)a1 << 16);
        }
    }
}

// ---------------- shared helpers ----------------
typedef __attribute__((address_space(1))) void as1_void;
typedef __attribute__((address_space(3))) void as3_void;

__device__ __forceinline__ void gload_lds16(const void* g, void* l) {
    // 16B direct global->LDS; dest is wave-uniform base + lane*16
    __builtin_amdgcn_global_load_lds((as1_void*)(void*)g, (as3_void*)l, 16, 0, 0);
}

// bf16 LDS tiles are [rows][64] (128B rows), XOR-swizzled: byte ^= (row&7)<<4
__device__ __forceinline__ bf16x8 frag_load(const unsigned short* base, int row, int kbyte) {
    kbyte ^= (row & 7) << 4;
    return *reinterpret_cast<const bf16x8*>(reinterpret_cast<const char*>(base) + row * 128 + kbyte);
}

// pack 8 f32 -> bf16x8 via v_cvt_pk_bf16_f32 (RTNE; bitwise == f2bf, verified R10)
__device__ __forceinline__ bf16x8 cvt8(const f32x4& lo, const f32x4& hi) {
    union { unsigned int u[4]; bf16x8 v; } r;
    asm("v_cvt_pk_bf16_f32 %0, %1, %2" : "=v"(r.u[0]) : "v"(lo[0]), "v"(lo[1]));
    asm("v_cvt_pk_bf16_f32 %0, %1, %2" : "=v"(r.u[1]) : "v"(lo[2]), "v"(lo[3]));
    asm("v_cvt_pk_bf16_f32 %0, %1, %2" : "=v"(r.u[2]) : "v"(hi[0]), "v"(hi[1]));
    asm("v_cvt_pk_bf16_f32 %0, %1, %2" : "=v"(r.u[3]) : "v"(hi[2]), "v"(hi[3]));
    return r.v;
}

// ---------------- GEMM1: chol = x @ W^T + b, diag-ReLU, store bf16 ----------------
// A is REG-STAGED from f32 x (load float4 x8 -> cvt_pk x16 -> ds_write_b128 x4),
// converting ONCE per k-tile in the staging phase; LDS tile stays bf16 16 KB
// (same layout/frag path as R5, 32 KB total -> 4 blocks/CU). B via gload_lds,
// issued FIRST so its DMA overlaps A's load latency. Kills the xb HBM roundtrip.
__global__ __launch_bounds__(256, 4) void gemm_kernel(const float* __restrict__ x,
                                                      const unsigned short* __restrict__ wb,
                                                      const float* __restrict__ biasf,
                                                      const float* __restrict__ diagm,
                                                      unsigned short* __restrict__ chol) {
    __shared__ __align__(16) unsigned short As[128 * 64];   // bf16, 16 KB
    __shared__ __align__(16) unsigned short Bs[128 * 64];   // bf16, 16 KB
    const int tid  = threadIdx.x;
    const int lane = tid & 63;
    const int wave = tid >> 6;

    // XCD-aware decode: grid 1088 = 8 XCDs x 136 chunks; XCD x owns m-tiles
    // [8x, 8x+8), n-fastest (x-panels + W stay resident in that XCD's L2).
    const int bid = blockIdx.x;
    const int xcd = bid & 7;
    const int c   = bid >> 3;            // 0..135
    const int mt  = xcd * 8 + c / 17;
    const int nt  = c % 17;
    const int m0 = mt * 128;
    const int n0 = nt * 128;

    const int wm = (wave >> 1) * 64;   // wave row offset in tile
    const int wn = (wave & 1) * 64;    // wave col offset in tile
    const int lr = lane & 15;
    const int lq = lane >> 4;

    f32x4 acc[4][4];
    f32x4 zero = {0.f, 0.f, 0.f, 0.f};
#pragma unroll
    for (int i = 0; i < 4; ++i)
#pragma unroll
        for (int j = 0; j < 4; ++j) acc[i][j] = zero;

    for (int k0 = 0; k0 < KDIM; k0 += 64) {
        const float*          ga = x  + (size_t)m0 * KDIM + k0;
        const unsigned short* gb = wb + (size_t)n0 * KDIM + k0;
        // B tile first: 128x64 bf16 = 1024 x 16B chunks via async gload_lds
#pragma unroll
        for (int cc = 0; cc < 4; ++cc) {
            int flat = cc * 256 + tid;
            int row  = flat >> 3;
            int ch   = (flat & 7) ^ (row & 7);
            unsigned short* lb = (unsigned short*)Bs + (size_t)(cc * 256 + (tid & 192)) * 8;
            gload_lds16(gb + row * KDIM + ch * 8, lb);
        }
        // A tile reg-staged: 4 chunks/thread; each chunk = 8 f32 = 2 float4
        f32x4 ra[8];
#pragma unroll
        for (int cc = 0; cc < 4; ++cc) {
            int flat = cc * 256 + tid;
            int row  = flat >> 3;
            int ch   = flat & 7;
            const float* src = ga + (size_t)row * KDIM + ch * 8;
            ra[cc * 2]     = *reinterpret_cast<const f32x4*>(src);
            ra[cc * 2 + 1] = *reinterpret_cast<const f32x4*>(src + 4);
        }
#pragma unroll
        for (int cc = 0; cc < 4; ++cc) {
            int flat = cc * 256 + tid;
            int row  = flat >> 3;
            int ch   = flat & 7;
            bf16x8 v = cvt8(ra[cc * 2], ra[cc * 2 + 1]);
            *reinterpret_cast<bf16x8*>((unsigned short*)As + row * 64 + ((ch ^ (row & 7)) * 8)) = v;
        }
        __syncthreads();   // drains vmcnt (B DMA) + lgkm (A ds_writes)
#pragma unroll
        for (int kk = 0; kk < 2; ++kk) {
            bf16x8 af[4], bf[4];
            int kb = kk * 64 + lq * 16;
#pragma unroll
            for (int i = 0; i < 4; ++i) {
                af[i] = frag_load(As, wm + i * 16 + lr, kb);
                bf[i] = frag_load(Bs, wn + i * 16 + lr, kb);
            }
#pragma unroll
            for (int mi = 0; mi < 4; ++mi)
#pragma unroll
                for (int ni = 0; ni < 4; ++ni)
                    acc[mi][ni] = __builtin_amdgcn_mfma_f32_16x16x32_bf16(bf[ni], af[mi], acc[mi][ni], 0, 0, 0);
        }
        __syncthreads();   // all waves done reading before next stage overwrites
    }

    // epilogue: acc[mi][ni] reg r -> chol[m][nb+r], m = m0+wm+mi*16+lr,
    // nb = n0+wn+ni*16+lq*4 (4-aligned -> float4 table loads, ushort4 store)
    const float4* bt = reinterpret_cast<const float4*>(biasf);
    const float4* dt = reinterpret_cast<const float4*>(diagm);
#pragma unroll
    for (int ni = 0; ni < 4; ++ni) {
        int nb = n0 + wn + ni * 16 + lq * 4;
        float4 bv = bt[nb >> 2];
        float4 dm = dt[nb >> 2];
#pragma unroll
        for (int mi = 0; mi < 4; ++mi) {
            int m = m0 + wm + mi * 16 + lr;
            float v0 = acc[mi][ni][0] + bv.x; if (dm.x != 0.f && v0 < 0.f) v0 = 0.f;
            float v1 = acc[mi][ni][1] + bv.y; if (dm.y != 0.f && v1 < 0.f) v1 = 0.f;
            float v2 = acc[mi][ni][2] + bv.z; if (dm.z != 0.f && v2 < 0.f) v2 = 0.f;
            float v3 = acc[mi][ni][3] + bv.w; if (dm.w != 0.f && v3 < 0.f) v3 = 0.f;
            *reinterpret_cast<ushort4*>(&chol[(size_t)m * NPAD + nb]) =
                make_ushort4(f2bf(v0), f2bf(v1), f2bf(v2), f2bf(v3));
        }
    }
}

// ---------------- SYRK: out[b] = L @ L^T (table scatter, LDS-bounced store) ----------------
__global__ __launch_bounds__(256) void syrk_kernel(const unsigned short* __restrict__ chol,
                                                   const unsigned int* __restrict__ sidx,
                                                   float* __restrict__ out) {
    __shared__ __align__(16) unsigned short Ls[4][64 * 64];
    const int tid  = threadIdx.x;
    const int lane = tid & 63;
    const int wave = tid >> 6;

    // XCD affinity with GEMM: XCD x produced batches [1024x, 1024x+1024).
    const int bid = blockIdx.x;
    const int bb  = (bid & 7) * 256 + (bid >> 3);
    const int batch = bb * 4 + wave;
    unsigned short* L = Ls[wave];

    // Issue all chol-row + scatter-address loads up front (coalesced, one wait)
    const unsigned int* row = reinterpret_cast<const unsigned int*>(chol + (size_t)batch * NPAD);
    unsigned int vals[17], adr[17];
#pragma unroll
    for (int c = 0; c < 17; ++c) {
        int t = lane + c * 64;
        vals[c] = (t < NSC) ? row[t] : 0u;
        adr[c]  = (t < NSC) ? sidx[t] : 0u;
    }

    // zero the tile (upper triangle must be 0) — wave-local LDS only
#pragma unroll
    for (int c = 0; c < 8; ++c)
        *reinterpret_cast<int4*>(reinterpret_cast<char*>(L) + (c * 64 + lane) * 16) = make_int4(0, 0, 0, 0);
    __builtin_amdgcn_sched_barrier(0);   // pin zero-writes before scatter-writes

    // scatter chol row into lower triangle via precomputed swizzled addresses
#pragma unroll
    for (int c = 0; c < 17; ++c) {
        int t = lane + c * 64;
        if (t < NSC) {
            unsigned int v = vals[c];
            unsigned int a = adr[c];
            *reinterpret_cast<unsigned short*>(reinterpret_cast<char*>(L) + (a & 0xffffu)) =
                (unsigned short)(v & 0xffffu);
            *reinterpret_cast<unsigned short*>(reinterpret_cast<char*>(L) + (a >> 16)) =
                (unsigned short)(v >> 16);
        }
    }
    // wave-local write->read ordering (no inter-wave sharing -> no s_barrier)
    asm volatile("s_waitcnt lgkmcnt(0)" ::: "memory");
    __builtin_amdgcn_sched_barrier(0);

    const int lr = lane & 15;
    const int lq = lane >> 4;
    // A and B fragments are identical reads (out = L @ L^T, B^T-form)
    bf16x8 fr[4][2];
#pragma unroll
    for (int i = 0; i < 4; ++i)
#pragma unroll
        for (int kk = 0; kk < 2; ++kk)
            fr[i][kk] = frag_load(L, i * 16 + lr, kk * 64 + lq * 16);

    f32x4 acc[4][4];
    f32x4 zero = {0.f, 0.f, 0.f, 0.f};
#pragma unroll
    for (int i = 0; i < 4; ++i)
#pragma unroll
        for (int j = 0; j < 4; ++j) acc[i][j] = zero;

#pragma unroll
    for (int mi = 0; mi < 4; ++mi)
#pragma unroll
        for (int ni = 0; ni < 4; ++ni)
#pragma unroll
            for (int kk = 0; kk < 2; ++kk)
                acc[mi][ni] = __builtin_amdgcn_mfma_f32_16x16x32_bf16(fr[mi][kk], fr[ni][kk], acc[mi][ni], 0, 0, 0);

    // Transposed acc layout (out symmetric): bounce through the wave's 8KB Ls
    // slice in two 32-row half-passes, store coalesced 1KB lines.
    float* fs = reinterpret_cast<float*>(L);   // 8KB = 32 rows x 64 f32
    float* ob = out + (size_t)batch * (MSZ * MSZ);
#pragma unroll
    for (int half = 0; half < 2; ++half) {
        asm volatile("s_waitcnt lgkmcnt(0)" ::: "memory");
        __builtin_amdgcn_sched_barrier(0);
#pragma unroll
        for (int ni2 = 0; ni2 < 2; ++ni2) {
            int ni = half * 2 + ni2;
            int r32 = ni2 * 16 + lr;             // row within half: 0..31
#pragma unroll
            for (int mi = 0; mi < 4; ++mi) {
                int byte = r32 * 256 + (mi * 16 + lq * 4) * 4;
                byte ^= (r32 & 7) << 4;
                *reinterpret_cast<f32x4*>(reinterpret_cast<char*>(fs) + byte) = acc[mi][ni];
            }
        }
        asm volatile("s_waitcnt lgkmcnt(0)" ::: "memory");
        __builtin_amdgcn_sched_barrier(0);
        // coalesced copy: 8KB per half = 8 instrs x (64 lanes x 16B contiguous)
#pragma unroll
        for (int c = 0; c < 8; ++c) {
            int off  = c * 1024 + lane * 16;      // byte offset within half
            int r32  = off >> 8;
            int byte = off ^ ((r32 & 7) << 4);
            f32x4 v = *reinterpret_cast<const f32x4*>(reinterpret_cast<const char*>(fs) + byte);
            *reinterpret_cast<f32x4*>(reinterpret_cast<char*>(ob) + half * 8192 + off) = v;
        }
    }
}

// ---------------- launch ----------------
extern "C" void kernel_launch(void* const* d_in, const int* in_sizes, int n_in,
                              void* d_out, int out_size, void* d_ws, size_t ws_size,
                              hipStream_t stream) {
    (void)in_sizes; (void)n_in; (void)out_size; (void)ws_size;
    const float* x = (const float*)d_in[0];   // [8192,512]
    const float* W = (const float*)d_in[1];   // [2080,512]
    const float* b = (const float*)d_in[2];   // [2080]
    float* out = (float*)d_out;               // [8192,64,64]

    unsigned short* wb   = (unsigned short*)d_ws;                 // 2176*512 bf16 (padded)
    unsigned short* chol = wb + (size_t)NPAD * KDIM;              // 8192*2176 bf16
    float* biasf = (float*)(chol + (size_t)MDIM * NPAD);          // 2176 f32
    float* diagm = biasf + NPAD;                                  // 2176 f32
    unsigned int* sidx = (unsigned int*)(diagm + NPAD);           // 1040 u32 scatter table

    int convw_blocks = (NW4 + NT4 + NSC + 255) / 256;
    convertw_kernel<<<dim3(convw_blocks), dim3(256), 0, stream>>>(W, b, wb, biasf, diagm, sidx);
    gemm_kernel<<<dim3(17 * 64), dim3(256), 0, stream>>>(x, wb, biasf, diagm, chol);
    syrk_kernel<<<dim3(MDIM / 4), dim3(256), 0, stream>>>(chol, sidx, out);
}

// Round 13
// 70.907 us; speedup vs baseline: 1.0711x; 1.0711x over previous
//
#include <hip/hip_runtime.h>
#include <stdint.h>

// Problem constants
#define MDIM 8192   // batch
#define KDIM 512    // input size
#define TDIM 2080   // tril param count (64*65/2)
#define NPAD 2176   // TDIM padded to multiple of 128 (17*128)
#define MSZ  64     // matrix size
#define NSC  1040   // chol-row dwords per batch (TDIM/2)

typedef __attribute__((ext_vector_type(8))) __bf16 bf16x8;
typedef __attribute__((ext_vector_type(4))) float  f32x4;

__device__ __forceinline__ unsigned short f2bf(float f) {
    unsigned int u = __float_as_uint(f);
    u += 0x7fffu + ((u >> 16) & 1u);   // round-to-nearest-even
    return (unsigned short)(u >> 16);
}

// tril row index from linear tril index n
__device__ __forceinline__ int tril_row(int n) {
    int i = (int)((sqrtf((float)(8 * n + 1)) - 1.0f) * 0.5f);
    while ((i + 1) * (i + 2) / 2 <= n) ++i;
    while (i * (i + 1) / 2 > n) --i;
    return i;
}

// swizzled LDS byte address for L[i][j] in the [64][64] bf16 tile
__device__ __forceinline__ int swz_addr(int i, int j) {
    int ch = ((j >> 3) ^ i) & 7;                         // swizzled 16B chunk
    return i * 128 + (ch << 4) + ((j & 7) * 2);
}

// ---------------- fused convert kernel (x, W, bias/diag tables, scatter table) ----------------
#define NX4 (MDIM * KDIM / 4)        // 1048576 float4 chunks of x
#define NW4 (NPAD * KDIM / 4)        // 278528 float4 chunks of padded W
#define NT4 (NPAD / 4)               // 544 table chunks

__global__ __launch_bounds__(256) void convert_kernel(const float* __restrict__ x,
                                                      const float* __restrict__ W,
                                                      const float* __restrict__ b,
                                                      unsigned short* __restrict__ xb,
                                                      unsigned short* __restrict__ wb,
                                                      float* __restrict__ biasf,
                                                      float* __restrict__ diagm,
                                                      unsigned int* __restrict__ sidx) {
    int idx = blockIdx.x * 256 + threadIdx.x;
    if (idx < NX4) {
        float4 v = reinterpret_cast<const float4*>(x)[idx];
        reinterpret_cast<ushort4*>(xb)[idx] =
            make_ushort4(f2bf(v.x), f2bf(v.y), f2bf(v.z), f2bf(v.w));
    } else if (idx < NX4 + NW4) {
        int j = idx - NX4;
        int n = (j * 4) >> 9;                            // W row (KDIM=512)
        ushort4 o = make_ushort4(0, 0, 0, 0);
        if (n < TDIM) {
            float4 v = reinterpret_cast<const float4*>(W)[j];
            o = make_ushort4(f2bf(v.x), f2bf(v.y), f2bf(v.z), f2bf(v.w));
        }
        reinterpret_cast<ushort4*>(wb)[j] = o;
    } else if (idx < NX4 + NW4 + NT4) {
        int t = idx - NX4 - NW4;
#pragma unroll
        for (int r = 0; r < 4; ++r) {
            int n = t * 4 + r;
            float bv = 0.f, dm = 0.f;
            if (n < TDIM) {
                bv = b[n];
                int i = tril_row(n);
                dm = (n - i * (i + 1) / 2 == i) ? 1.f : 0.f;
            }
            biasf[n] = bv;
            diagm[n] = dm;
        }
    } else {
        int t = idx - NX4 - NW4 - NT4;                   // scatter-table entry (chol dword)
        if (t < NSC) {
            int n = 2 * t;
            int i = tril_row(n);
            int j = n - i * (i + 1) / 2;
            int a0 = swz_addr(i, j);
            int i2 = i, j2 = j + 1;
            if (j2 > i2) { i2 = i + 1; j2 = 0; }
            int a1 = swz_addr(i2, j2);
            sidx[t] = (unsigned int)a0 | ((unsigned int)a1 << 16);
        }
    }
}

// ---------------- shared helpers ----------------
typedef __attribute__((address_space(1))) void as1_void;
typedef __attribute__((address_space(3))) void as3_void;

__device__ __forceinline__ void gload_lds16(const void* g, void* l) {
    // 16B direct global->LDS; dest is wave-uniform base + lane*16
    __builtin_amdgcn_global_load_lds((as1_void*)(void*)g, (as3_void*)l, 16, 0, 0);
}

// LDS tiles are [rows][64] bf16 (128B rows), XOR-swizzled: byte ^= (row&7)<<4
__device__ __forceinline__ bf16x8 frag_load(const unsigned short* base, int row, int kbyte) {
    kbyte ^= (row & 7) << 4;
    return *reinterpret_cast<const bf16x8*>(reinterpret_cast<const char*>(base) + row * 128 + kbyte);
}

// ---------------- GEMM1: chol = x @ W^T + b, diag-ReLU, store bf16 (R5-proven) ----------------
// Swapped-operand MFMA (mfma(B,A)): acc regs hold 4 consecutive n at fixed m
// -> 8B chol stores, table-driven bias/ReLU (no sqrt in epilogue).
__global__ __launch_bounds__(256, 4) void gemm_kernel(const unsigned short* __restrict__ xb,
                                                      const unsigned short* __restrict__ wb,
                                                      const float* __restrict__ biasf,
                                                      const float* __restrict__ diagm,
                                                      unsigned short* __restrict__ chol) {
    __shared__ __align__(16) unsigned short As[128 * 64];
    __shared__ __align__(16) unsigned short Bs[128 * 64];
    const int tid  = threadIdx.x;
    const int lane = tid & 63;
    const int wave = tid >> 6;

    // XCD-aware decode: grid 1088 = 8 XCDs x 136 chunks; XCD x owns m-tiles
    // [8x, 8x+8), n-fastest (A-panels + W stay resident in that XCD's L2).
    const int bid = blockIdx.x;
    const int xcd = bid & 7;
    const int c   = bid >> 3;            // 0..135
    const int mt  = xcd * 8 + c / 17;
    const int nt  = c % 17;
    const int m0 = mt * 128;
    const int n0 = nt * 128;

    const int wm = (wave >> 1) * 64;   // wave row offset in tile
    const int wn = (wave & 1) * 64;    // wave col offset in tile
    const int lr = lane & 15;
    const int lq = lane >> 4;

    f32x4 acc[4][4];
    f32x4 zero = {0.f, 0.f, 0.f, 0.f};
#pragma unroll
    for (int i = 0; i < 4; ++i)
#pragma unroll
        for (int j = 0; j < 4; ++j) acc[i][j] = zero;

    for (int k0 = 0; k0 < KDIM; k0 += 64) {
        const unsigned short* ga = xb + (size_t)m0 * KDIM + k0;
        const unsigned short* gb = wb + (size_t)n0 * KDIM + k0;
        // stage A tile: 128x64 bf16 = 1024 x 16B chunks; pre-swizzled global source
#pragma unroll
        for (int cc = 0; cc < 4; ++cc) {
            int flat = cc * 256 + tid;
            int row  = flat >> 3;
            int ch   = (flat & 7) ^ (row & 7);
            unsigned short* lb = (unsigned short*)As + (size_t)(cc * 256 + (tid & 192)) * 8;
            gload_lds16(ga + row * KDIM + ch * 8, lb);
        }
#pragma unroll
        for (int cc = 0; cc < 4; ++cc) {
            int flat = cc * 256 + tid;
            int row  = flat >> 3;
            int ch   = (flat & 7) ^ (row & 7);
            unsigned short* lb = (unsigned short*)Bs + (size_t)(cc * 256 + (tid & 192)) * 8;
            gload_lds16(gb + row * KDIM + ch * 8, lb);
        }
        __syncthreads();   // drains vmcnt -> staged data visible
#pragma unroll
        for (int kk = 0; kk < 2; ++kk) {
            bf16x8 af[4], bf[4];
            int kb = kk * 64 + lq * 16;
#pragma unroll
            for (int i = 0; i < 4; ++i) {
                af[i] = frag_load(As, wm + i * 16 + lr, kb);
                bf[i] = frag_load(Bs, wn + i * 16 + lr, kb);
            }
#pragma unroll
            for (int mi = 0; mi < 4; ++mi)
#pragma unroll
                for (int ni = 0; ni < 4; ++ni)
                    acc[mi][ni] = __builtin_amdgcn_mfma_f32_16x16x32_bf16(bf[ni], af[mi], acc[mi][ni], 0, 0, 0);
        }
        __syncthreads();   // all waves done reading before next stage overwrites
    }

    // epilogue: acc[mi][ni] reg r -> chol[m][nb+r], m = m0+wm+mi*16+lr,
    // nb = n0+wn+ni*16+lq*4 (4-aligned -> float4 table loads, ushort4 store)
    const float4* bt = reinterpret_cast<const float4*>(biasf);
    const float4* dt = reinterpret_cast<const float4*>(diagm);
#pragma unroll
    for (int ni = 0; ni < 4; ++ni) {
        int nb = n0 + wn + ni * 16 + lq * 4;
        float4 bv = bt[nb >> 2];
        float4 dm = dt[nb >> 2];
#pragma unroll
        for (int mi = 0; mi < 4; ++mi) {
            int m = m0 + wm + mi * 16 + lr;
            float v0 = acc[mi][ni][0] + bv.x; if (dm.x != 0.f && v0 < 0.f) v0 = 0.f;
            float v1 = acc[mi][ni][1] + bv.y; if (dm.y != 0.f && v1 < 0.f) v1 = 0.f;
            float v2 = acc[mi][ni][2] + bv.z; if (dm.z != 0.f && v2 < 0.f) v2 = 0.f;
            float v3 = acc[mi][ni][3] + bv.w; if (dm.w != 0.f && v3 < 0.f) v3 = 0.f;
            *reinterpret_cast<ushort4*>(&chol[(size_t)m * NPAD + nb]) =
                make_ushort4(f2bf(v0), f2bf(v1), f2bf(v2), f2bf(v3));
        }
    }
}

// ---------------- SYRK: out[b] = L @ L^T (table-driven scatter) ----------------
__global__ __launch_bounds__(256) void syrk_kernel(const unsigned short* __restrict__ chol,
                                                   const unsigned int* __restrict__ sidx,
                                                   float* __restrict__ out) {
    __shared__ __align__(16) unsigned short Ls[4][64 * 64];
    const int tid  = threadIdx.x;
    const int lane = tid & 63;
    const int wave = tid >> 6;

    // XCD affinity with GEMM: XCD x produced batches [1024x, 1024x+1024).
    const int bid = blockIdx.x;
    const int bb  = (bid & 7) * 256 + (bid >> 3);
    const int batch = bb * 4 + wave;
    unsigned short* L = Ls[wave];

    // Issue all chol-row + scatter-address loads up front (coalesced, one wait)
    const unsigned int* row = reinterpret_cast<const unsigned int*>(chol + (size_t)batch * NPAD);
    unsigned int vals[17], adr[17];
#pragma unroll
    for (int c = 0; c < 17; ++c) {
        int t = lane + c * 64;
        vals[c] = (t < NSC) ? row[t] : 0u;
        adr[c]  = (t < NSC) ? sidx[t] : 0u;
    }

    // zero the tile (upper triangle must be 0) — wave-local LDS only
#pragma unroll
    for (int c = 0; c < 8; ++c)
        *reinterpret_cast<int4*>(reinterpret_cast<char*>(L) + (c * 64 + lane) * 16) = make_int4(0, 0, 0, 0);
    __builtin_amdgcn_sched_barrier(0);   // pin zero-writes before scatter-writes

    // scatter chol row into lower triangle via precomputed swizzled addresses
#pragma unroll
    for (int c = 0; c < 17; ++c) {
        int t = lane + c * 64;
        if (t < NSC) {
            unsigned int v = vals[c];
            unsigned int a = adr[c];
            *reinterpret_cast<unsigned short*>(reinterpret_cast<char*>(L) + (a & 0xffffu)) =
                (unsigned short)(v & 0xffffu);
            *reinterpret_cast<unsigned short*>(reinterpret_cast<char*>(L) + (a >> 16)) =
                (unsigned short)(v >> 16);
        }
    }
    // wave-local write->read ordering (no inter-wave sharing -> no s_barrier)
    asm volatile("s_waitcnt lgkmcnt(0)" ::: "memory");
    __builtin_amdgcn_sched_barrier(0);

    const int lr = lane & 15;
    const int lq = lane >> 4;
    // A and B fragments are identical reads (out = L @ L^T, B^T-form)
    bf16x8 fr[4][2];
#pragma unroll
    for (int i = 0; i < 4; ++i)
#pragma unroll
        for (int kk = 0; kk < 2; ++kk)
            fr[i][kk] = frag_load(L, i * 16 + lr, kk * 64 + lq * 16);

    f32x4 acc[4][4];
    f32x4 zero = {0.f, 0.f, 0.f, 0.f};
#pragma unroll
    for (int i = 0; i < 4; ++i)
#pragma unroll
        for (int j = 0; j < 4; ++j) acc[i][j] = zero;

#pragma unroll
    for (int mi = 0; mi < 4; ++mi)
#pragma unroll
        for (int ni = 0; ni < 4; ++ni)
#pragma unroll
            for (int kk = 0; kk < 2; ++kk)
                acc[mi][ni] = __builtin_amdgcn_mfma_f32_16x16x32_bf16(fr[mi][kk], fr[ni][kk], acc[mi][ni], 0, 0, 0);

    // out is symmetric: store acc[mi][ni] at the TRANSPOSED location so the 4
    // accumulator regs are contiguous -> 16x global_store_dwordx4
    float* ob = out + (size_t)batch * (MSZ * MSZ);
#pragma unroll
    for (int mi = 0; mi < 4; ++mi)
#pragma unroll
        for (int ni = 0; ni < 4; ++ni)
            *reinterpret_cast<f32x4*>(ob + (ni * 16 + lr) * MSZ + mi * 16 + lq * 4) = acc[mi][ni];
}

// ---------------- launch ----------------
extern "C" void kernel_launch(void* const* d_in, const int* in_sizes, int n_in,
                              void* d_out, int out_size, void* d_ws, size_t ws_size,
                              hipStream_t stream) {
    (void)in_sizes; (void)n_in; (void)out_size; (void)ws_size;
    const float* x = (const float*)d_in[0];   // [8192,512]
    const float* W = (const float*)d_in[1];   // [2080,512]
    const float* b = (const float*)d_in[2];   // [2080]
    float* out = (float*)d_out;               // [8192,64,64]

    unsigned short* xb   = (unsigned short*)d_ws;                 // 8192*512 bf16
    unsigned short* wb   = xb + (size_t)MDIM * KDIM;              // 2176*512 bf16 (padded)
    unsigned short* chol = wb + (size_t)NPAD * KDIM;              // 8192*2176 bf16
    float* biasf = (float*)(chol + (size_t)MDIM * NPAD);          // 2176 f32
    float* diagm = biasf + NPAD;                                  // 2176 f32
    unsigned int* sidx = (unsigned int*)(diagm + NPAD);           // 1040 u32 scatter table

    int conv_blocks = (NX4 + NW4 + NT4 + NSC + 255) / 256;
    convert_kernel<<<dim3(conv_blocks), dim3(256), 0, stream>>>(x, W, b, xb, wb, biasf, diagm, sidx);
    gemm_kernel<<<dim3(17 * 64), dim3(256), 0, stream>>>(xb, wb, biasf, diagm, chol);
    syrk_kernel<<<dim3(MDIM / 4), dim3(256), 0, stream>>>(chol, sidx, out);
}